// Round 10
// baseline (137.039 us; speedup 1.0000x reference)
//
#include <hip/hip_runtime.h>
#include <hip/hip_bf16.h>
#include <cstdint>

#define SEQ   2048
#define HD    64
#define NBH   32
#define QBLK  64
#define KVBLK 64
#define NQT   (SEQ / QBLK)  // 32
#define LDK   72            // padded LDS stride (shorts): 144B rows
// scale = 1/sqrt(64) * log2(e)  (softmax in exp2 domain)
#define QSC   0.18033688011112042f
#define THR   11.0f         // defer-max threshold (log2 domain)

typedef __attribute__((ext_vector_type(8))) short short8;
typedef __attribute__((ext_vector_type(4))) float floatx4;

#if __has_builtin(__builtin_amdgcn_exp2f)
#define EXP2(x) __builtin_amdgcn_exp2f(x)
#else
#define EXP2(x) __expf((x) * 0.69314718055994531f)
#endif

static __device__ __forceinline__ short f2bf(float f) {
    union { float f; unsigned u; } x; x.f = f;
    return (short)((x.u + 0x7fffu + ((x.u >> 16) & 1u)) >> 16);  // RNE
}
static __device__ __forceinline__ unsigned pkbf(float a, float b) {
    __hip_bfloat162 h = __float22bfloat162_rn(make_float2(a, b));
    union { __hip_bfloat162 h; unsigned u; } c; c.h = h; return c.u;
}

// ---------------- prep kernels (proven) ----------------

__global__ __launch_bounds__(256)
void conv_k_kernel(const float* __restrict__ K, short* __restrict__ Kb) {
    size_t i = ((size_t)blockIdx.x * 256 + threadIdx.x) * 8;
    float4 a = *(const float4*)(K + i);
    float4 b = *(const float4*)(K + i + 4);
    union { unsigned u[4]; short8 s; } cv;
    cv.u[0] = pkbf(a.x, a.y); cv.u[1] = pkbf(a.z, a.w);
    cv.u[2] = pkbf(b.x, b.y); cv.u[3] = pkbf(b.z, b.w);
    *(short8*)(Kb + i) = cv.s;
}

__global__ __launch_bounds__(256)
void trans_v_kernel(const float* __restrict__ V, short* __restrict__ Vt) {
    __shared__ __align__(16) short Vs[64][72];
    const int tid = threadIdx.x;
    const int bh = blockIdx.x >> 5;
    const int t  = blockIdx.x & 31;
    const float* src = V + ((size_t)bh * SEQ + (size_t)t * 64) * HD;
    #pragma unroll
    for (int i = 0; i < 4; ++i) {
        int idx = i * 256 + tid;
        int r = idx >> 4; int c = (idx & 15) * 4;
        float4 f = *(const float4*)(src + r * HD + c);
        Vs[c + 0][r] = f2bf(f.x); Vs[c + 1][r] = f2bf(f.y);
        Vs[c + 2][r] = f2bf(f.z); Vs[c + 3][r] = f2bf(f.w);
    }
    __syncthreads();
    short* dst = Vt + (size_t)bh * HD * SEQ + t * 64;
    #pragma unroll
    for (int i = 0; i < 2; ++i) {
        int idx = i * 256 + tid;
        int d = idx >> 3; int j = idx & 7;
        short8 v = *(const short8*)&Vs[d][j * 8];
        *(short8*)(dst + (size_t)d * SEQ + j * 8) = v;
    }
}

// ---------------- main attention kernel (v10) ----------------
// v9 structure (1024 heavy-first blocks, swapped QK^T, zero-LDS P via K-row
// permutation {0,4,32,36}, defer-max, setprio, dbuf K staging w/ reg-prefetch)
// + V DIRECT FROM GLOBAL (L2-resident; LDS ops/tile halved, LDS 18.4 KB)
// + SPECULATIVE exp2 with old max (rare recompute on defer-max trigger).

__global__ __launch_bounds__(256, 4)
void fa_fwd_v10(const float* __restrict__ Q, const short* __restrict__ Kg,
                const short* __restrict__ Vtg, float* __restrict__ O)
{
    const int tid  = threadIdx.x;
    const int lane = tid & 63;
    const int wv   = tid >> 6;
    const int l15  = lane & 15;
    const int lg   = lane >> 4;
    const int lg4  = lg * 4;
    const int dofs = lg * 8;

    const int bh = blockIdx.x & (NBH - 1);
    const int qi = (NQT - 1) - (blockIdx.x >> 5);   // heavy tiles first
    const int qbase = qi * QBLK;

    const float* Qp = Q   + (size_t)bh * SEQ * HD;
    const short* Kp = Kg  + (size_t)bh * SEQ * HD;
    const short* Vp = Vtg + (size_t)bh * HD * SEQ;
    float*       Op = O   + (size_t)bh * SEQ * HD;

    __shared__ __align__(16) short K_lds[2][KVBLK][LDK];   // 18.4 KB

    // K staging: 512 x 16B chunks per tile; 2 per thread
    const int r0 = tid >> 3,         j0 = tid & 7;
    const int r1 = (tid + 256) >> 3, j1 = tid & 7;
    const int kg0 = r0 * HD + j0 * 8, kg1 = r1 * HD + j1 * 8;

    // permuted K-row base: call n reads row rowb + {0,4,32,36}[n]
    const int rowb = ((l15 & ~3) << 1) + (l15 & 3);   // 8*(l15>>2) + (l15&3)
    const int kb   = 8 * lg;                           // lane's k base

    // ---- Q fragments (B-operand), scale folded ----
    short8 qf0, qf1;
    {
        const float* src = Qp + (size_t)(qbase + wv * 16 + l15) * HD + dofs;
        union { unsigned u[4]; short8 s; } cv;
        float4 f0 = *(const float4*)(src);
        float4 f1 = *(const float4*)(src + 4);
        cv.u[0] = pkbf(f0.x * QSC, f0.y * QSC); cv.u[1] = pkbf(f0.z * QSC, f0.w * QSC);
        cv.u[2] = pkbf(f1.x * QSC, f1.y * QSC); cv.u[3] = pkbf(f1.z * QSC, f1.w * QSC);
        qf0 = cv.s;
        f0 = *(const float4*)(src + 32);
        f1 = *(const float4*)(src + 36);
        cv.u[0] = pkbf(f0.x * QSC, f0.y * QSC); cv.u[1] = pkbf(f0.z * QSC, f0.w * QSC);
        cv.u[2] = pkbf(f1.x * QSC, f1.y * QSC); cv.u[3] = pkbf(f1.z * QSC, f1.w * QSC);
        qf1 = cv.s;
    }

    // ---- prologue: prefetch K tile 0 ----
    short8 krA = *(const short8*)(Kp + kg0);
    short8 krB = *(const short8*)(Kp + kg1);

    floatx4 o_acc[4];
    #pragma unroll
    for (int dt = 0; dt < 4; ++dt)
        #pragma unroll
        for (int e = 0; e < 4; ++e) o_acc[dt][e] = 0.0f;
    float m_s = -1e30f, l_s = 0.0f;

    for (int t = 0; t <= qi; ++t) {
        const int buf = t & 1;
        *(short8*)&K_lds[buf][r0][j0 * 8] = krA;
        *(short8*)&K_lds[buf][r1][j1 * 8] = krB;
        __syncthreads();

        // ---- V fragments direct from global (L2-resident); consumed at PV ----
        short8 vA[4], vB[4];
        #pragma unroll
        for (int dt = 0; dt < 4; ++dt) {
            const short* vr = Vp + (size_t)(dt * 16 + l15) * SEQ + t * KVBLK + dofs;
            vA[dt] = *(const short8*)(vr);
            vB[dt] = *(const short8*)(vr + 32);
        }

        // ---- prefetch K tile t+1 ----
        if (t < qi) {
            const short* ks = Kp + (size_t)(t + 1) * KVBLK * HD;
            krA = *(const short8*)(ks + kg0);
            krB = *(const short8*)(ks + kg1);
        }

        // ---- S^T = K (Q*scale)^T with permuted rows:
        //      s_acc[n][r] = S[k = kb + roff[n] + r][q = l15] ----
        const int roff[4] = {0, 4, 32, 36};
        floatx4 s_acc[4];
        __builtin_amdgcn_s_setprio(1);
        #pragma unroll
        for (int n = 0; n < 4; ++n) {
            const short* krow = &K_lds[buf][rowb + roff[n]][0];
            const short8 k0 = *(const short8*)(krow + dofs);
            const short8 k1 = *(const short8*)(krow + dofs + 32);
            floatx4 acc = {0.0f, 0.0f, 0.0f, 0.0f};
            acc = __builtin_amdgcn_mfma_f32_16x16x32_bf16(k0, qf0, acc, 0, 0, 0);
            acc = __builtin_amdgcn_mfma_f32_16x16x32_bf16(k1, qf1, acc, 0, 0, 0);
            s_acc[n] = acc;
        }
        __builtin_amdgcn_s_setprio(0);

        // ---- causal mask (diagonal tile only): k_local > q_local ----
        if (t == qi) {
            const int qlocal = wv * 16 + l15;
            #pragma unroll
            for (int n = 0; n < 4; ++n)
                #pragma unroll
                for (int r = 0; r < 4; ++r)
                    if (kb + roff[n] + r > qlocal) s_acc[n][r] = -1e30f;
        }

        // ---- SPECULATIVE P = exp2(S - m_old); max-tree runs in parallel ----
        float p00 = EXP2(s_acc[0][0] - m_s), p01 = EXP2(s_acc[0][1] - m_s);
        float p02 = EXP2(s_acc[0][2] - m_s), p03 = EXP2(s_acc[0][3] - m_s);
        float p10 = EXP2(s_acc[1][0] - m_s), p11 = EXP2(s_acc[1][1] - m_s);
        float p12 = EXP2(s_acc[1][2] - m_s), p13 = EXP2(s_acc[1][3] - m_s);
        float p20 = EXP2(s_acc[2][0] - m_s), p21 = EXP2(s_acc[2][1] - m_s);
        float p22 = EXP2(s_acc[2][2] - m_s), p23 = EXP2(s_acc[2][3] - m_s);
        float p30 = EXP2(s_acc[3][0] - m_s), p31 = EXP2(s_acc[3][1] - m_s);
        float p32 = EXP2(s_acc[3][2] - m_s), p33 = EXP2(s_acc[3][3] - m_s);
        float lsum = ((p00 + p01) + (p02 + p03)) + ((p10 + p11) + (p12 + p13))
                   + ((p20 + p21) + (p22 + p23)) + ((p30 + p31) + (p32 + p33));

        float t0 = fmaxf(fmaxf(s_acc[0][0], s_acc[0][1]), fmaxf(s_acc[0][2], s_acc[0][3]));
        float t1 = fmaxf(fmaxf(s_acc[1][0], s_acc[1][1]), fmaxf(s_acc[1][2], s_acc[1][3]));
        float t2 = fmaxf(fmaxf(s_acc[2][0], s_acc[2][1]), fmaxf(s_acc[2][2], s_acc[2][3]));
        float t3 = fmaxf(fmaxf(s_acc[3][0], s_acc[3][1]), fmaxf(s_acc[3][2], s_acc[3][3]));
        float rmax = fmaxf(fmaxf(t0, t1), fmaxf(t2, t3));
        rmax = fmaxf(rmax, __shfl_xor(rmax, 16));
        rmax = fmaxf(rmax, __shfl_xor(rmax, 32));

        const bool trig = rmax > m_s + THR;
        if (__any(trig)) {                       // rare after the first tile
            float alpha = 1.0f;
            if (trig) {
                alpha = EXP2(m_s - rmax);        // exact; 0 on first tile
                m_s = rmax;
                // recompute with the new max (avoids inf*0 on first tile)
                p00 = EXP2(s_acc[0][0] - m_s); p01 = EXP2(s_acc[0][1] - m_s);
                p02 = EXP2(s_acc[0][2] - m_s); p03 = EXP2(s_acc[0][3] - m_s);
                p10 = EXP2(s_acc[1][0] - m_s); p11 = EXP2(s_acc[1][1] - m_s);
                p12 = EXP2(s_acc[1][2] - m_s); p13 = EXP2(s_acc[1][3] - m_s);
                p20 = EXP2(s_acc[2][0] - m_s); p21 = EXP2(s_acc[2][1] - m_s);
                p22 = EXP2(s_acc[2][2] - m_s); p23 = EXP2(s_acc[2][3] - m_s);
                p30 = EXP2(s_acc[3][0] - m_s); p31 = EXP2(s_acc[3][1] - m_s);
                p32 = EXP2(s_acc[3][2] - m_s); p33 = EXP2(s_acc[3][3] - m_s);
                lsum = ((p00 + p01) + (p02 + p03)) + ((p10 + p11) + (p12 + p13))
                     + ((p20 + p21) + (p22 + p23)) + ((p30 + p31) + (p32 + p33));
            }
            l_s = l_s * alpha + lsum;
            // o_acc row e is q=lg4+e; alpha for q lives in lane l15==q (lg=0)
            float a0 = __shfl(alpha, lg4 + 0);
            float a1 = __shfl(alpha, lg4 + 1);
            float a2 = __shfl(alpha, lg4 + 2);
            float a3 = __shfl(alpha, lg4 + 3);
            #pragma unroll
            for (int dt = 0; dt < 4; ++dt) {
                o_acc[dt][0] *= a0; o_acc[dt][1] *= a1;
                o_acc[dt][2] *= a2; o_acc[dt][3] *= a3;
            }
        } else {
            l_s += lsum;
        }

        // ---- pack P into PV A-fragments (in-register, zero LDS) ----
        short8 p0, p1;
        {
            union { unsigned u[4]; short8 s; } c0, c1;
            c0.u[0] = pkbf(p00, p01); c0.u[1] = pkbf(p02, p03);   // k = kb+0..3
            c0.u[2] = pkbf(p10, p11); c0.u[3] = pkbf(p12, p13);   // k = kb+4..7
            c1.u[0] = pkbf(p20, p21); c1.u[1] = pkbf(p22, p23);   // k = 32+kb+0..3
            c1.u[2] = pkbf(p30, p31); c1.u[3] = pkbf(p32, p33);   // k = 32+kb+4..7
            p0 = c0.s; p1 = c1.s;
        }

        // ---- O += P V (V in regs from global) ----
        __builtin_amdgcn_s_setprio(1);
        #pragma unroll
        for (int dt = 0; dt < 4; ++dt) {
            o_acc[dt] = __builtin_amdgcn_mfma_f32_16x16x32_bf16(p0, vA[dt], o_acc[dt], 0, 0, 0);
            o_acc[dt] = __builtin_amdgcn_mfma_f32_16x16x32_bf16(p1, vB[dt], o_acc[dt], 0, 0, 0);
        }
        __builtin_amdgcn_s_setprio(0);
    }

    // ---- finalize ----
    l_s += __shfl_xor(l_s, 16);
    l_s += __shfl_xor(l_s, 32);
    const float linv = 1.0f / l_s;
    #pragma unroll
    for (int e = 0; e < 4; ++e) {
        const float li = __shfl(linv, lg4 + e);
        const int row = qbase + wv * 16 + lg4 + e;
        #pragma unroll
        for (int dt = 0; dt < 4; ++dt)
            Op[(size_t)row * HD + dt * 16 + l15] = o_acc[dt][e] * li;
    }
}

// ---------------- fallback (round-1 kernel, proven) if ws too small ----------------

__global__ __launch_bounds__(256, 2)
void fa_fwd_v1(const float* __restrict__ Q, const float* __restrict__ K,
               const float* __restrict__ V, float* __restrict__ O)
{
    const int tid  = threadIdx.x;
    const int lane = tid & 63;
    const int wv   = tid >> 6;
    const int l15  = lane & 15;
    const int lg   = lane >> 4;
    const int dofs = lg * 8;
    const int bh = blockIdx.x & (NBH - 1);
    const int qi = 31 - (blockIdx.x >> 5);
    const size_t base = (size_t)bh * SEQ * HD;
    const float* Qp = Q + base; const float* Kp = K + base;
    const float* Vp = V + base; float* Op = O + base;
    const int qbase = qi * 64;
    __shared__ __align__(16) short K_lds[64][72];
    __shared__ __align__(16) short Vt_lds[HD][72];
    __shared__ __align__(16) short P_lds[4][16][72];
    short8 qfrag[2];
    {
        const float* src = Qp + (size_t)(qbase + wv * 16 + l15) * HD + dofs;
        #pragma unroll
        for (int c = 0; c < 2; ++c) {
            float4 f0 = *(const float4*)(src + 32 * c);
            float4 f1 = *(const float4*)(src + 32 * c + 4);
            short8 tt;
            tt[0] = f2bf(f0.x * 0.125f); tt[1] = f2bf(f0.y * 0.125f);
            tt[2] = f2bf(f0.z * 0.125f); tt[3] = f2bf(f0.w * 0.125f);
            tt[4] = f2bf(f1.x * 0.125f); tt[5] = f2bf(f1.y * 0.125f);
            tt[6] = f2bf(f1.z * 0.125f); tt[7] = f2bf(f1.w * 0.125f);
            qfrag[c] = tt;
        }
    }
    floatx4 o_acc[4];
    #pragma unroll
    for (int dt = 0; dt < 4; ++dt)
        #pragma unroll
        for (int e = 0; e < 4; ++e) o_acc[dt][e] = 0.0f;
    float m_r[4], l_r[4];
    #pragma unroll
    for (int r = 0; r < 4; ++r) { m_r[r] = -1e30f; l_r[r] = 0.0f; }
    for (int t = 0; t <= qi; ++t) {
        __syncthreads();
        {
            const float4* ks = (const float4*)(Kp + (size_t)t * 64 * HD);
            const float4* vs = (const float4*)(Vp + (size_t)t * 64 * HD);
            #pragma unroll
            for (int j = 0; j < 4; ++j) {
                int idx = j * 256 + tid;
                int row = idx >> 4;
                int col = (idx & 15) << 2;
                float4 kf = ks[idx];
                K_lds[row][col + 0] = f2bf(kf.x); K_lds[row][col + 1] = f2bf(kf.y);
                K_lds[row][col + 2] = f2bf(kf.z); K_lds[row][col + 3] = f2bf(kf.w);
                float4 vf = vs[idx];
                Vt_lds[col + 0][row] = f2bf(vf.x); Vt_lds[col + 1][row] = f2bf(vf.y);
                Vt_lds[col + 2][row] = f2bf(vf.z); Vt_lds[col + 3][row] = f2bf(vf.w);
            }
        }
        __syncthreads();
        floatx4 s_acc[4];
        #pragma unroll
        for (int n = 0; n < 4; ++n) {
            const short8 k0 = *(const short8*)&K_lds[n * 16 + l15][dofs];
            const short8 k1 = *(const short8*)&K_lds[n * 16 + l15][dofs + 32];
            floatx4 acc = {0.0f, 0.0f, 0.0f, 0.0f};
            acc = __builtin_amdgcn_mfma_f32_16x16x32_bf16(qfrag[0], k0, acc, 0, 0, 0);
            acc = __builtin_amdgcn_mfma_f32_16x16x32_bf16(qfrag[1], k1, acc, 0, 0, 0);
            s_acc[n] = acc;
        }
        if (t == qi) {
            #pragma unroll
            for (int n = 0; n < 4; ++n)
                #pragma unroll
                for (int r = 0; r < 4; ++r) {
                    int qr = wv * 16 + lg * 4 + r;
                    int kc = n * 16 + l15;
                    if (kc > qr) s_acc[n][r] = -1e30f;
                }
        }
        #pragma unroll
        for (int r = 0; r < 4; ++r) {
            float rmax = fmaxf(fmaxf(s_acc[0][r], s_acc[1][r]),
                               fmaxf(s_acc[2][r], s_acc[3][r]));
            rmax = fmaxf(rmax, __shfl_xor(rmax, 1));
            rmax = fmaxf(rmax, __shfl_xor(rmax, 2));
            rmax = fmaxf(rmax, __shfl_xor(rmax, 4));
            rmax = fmaxf(rmax, __shfl_xor(rmax, 8));
            float mnew  = fmaxf(m_r[r], rmax);
            float alpha = __expf(m_r[r] - mnew);
            m_r[r] = mnew;
            l_r[r] *= alpha;
            #pragma unroll
            for (int dt = 0; dt < 4; ++dt) o_acc[dt][r] *= alpha;
            #pragma unroll
            for (int n = 0; n < 4; ++n) {
                float p = __expf(s_acc[n][r] - mnew);
                l_r[r] += p;
                P_lds[wv][lg * 4 + r][n * 16 + l15] = f2bf(p);
            }
        }
        asm volatile("s_waitcnt lgkmcnt(0)" ::: "memory");
        const short8 p0 = *(const short8*)&P_lds[wv][l15][dofs];
        const short8 p1 = *(const short8*)&P_lds[wv][l15][dofs + 32];
        #pragma unroll
        for (int dt = 0; dt < 4; ++dt) {
            const short8 v0 = *(const short8*)&Vt_lds[dt * 16 + l15][dofs];
            const short8 v1 = *(const short8*)&Vt_lds[dt * 16 + l15][dofs + 32];
            o_acc[dt] = __builtin_amdgcn_mfma_f32_16x16x32_bf16(p0, v0, o_acc[dt], 0, 0, 0);
            o_acc[dt] = __builtin_amdgcn_mfma_f32_16x16x32_bf16(p1, v1, o_acc[dt], 0, 0, 0);
        }
    }
    #pragma unroll
    for (int r = 0; r < 4; ++r) {
        float l = l_r[r];
        l += __shfl_xor(l, 1);
        l += __shfl_xor(l, 2);
        l += __shfl_xor(l, 4);
        l += __shfl_xor(l, 8);
        l_r[r] = 1.0f / l;
    }
    #pragma unroll
    for (int dt = 0; dt < 4; ++dt)
        #pragma unroll
        for (int r = 0; r < 4; ++r) {
            int row = qbase + wv * 16 + lg * 4 + r;
            Op[(size_t)row * HD + dt * 16 + l15] = o_acc[dt][r] * l_r[r];
        }
}

extern "C" void kernel_launch(void* const* d_in, const int* in_sizes, int n_in,
                              void* d_out, int out_size, void* d_ws, size_t ws_size,
                              hipStream_t stream) {
    const float* q = (const float*)d_in[0];
    const float* k = (const float*)d_in[1];
    const float* v = (const float*)d_in[2];
    float* o = (float*)d_out;
    (void)in_sizes; (void)n_in; (void)out_size;

    const size_t elems = (size_t)NBH * SEQ * HD;
    const size_t need  = 2 * elems * sizeof(short);
    if (ws_size >= need) {
        short* kb = (short*)d_ws;
        short* vt = kb + elems;
        conv_k_kernel<<<dim3(elems / (256 * 8)), dim3(256), 0, stream>>>(k, kb);
        trans_v_kernel<<<dim3(NBH * 32), dim3(256), 0, stream>>>(v, vt);
        fa_fwd_v10<<<dim3(NBH * NQT), dim3(256), 0, stream>>>(q, kb, vt, o);
    } else {
        fa_fwd_v1<<<dim3(NBH * 32), dim3(256), 0, stream>>>(q, k, v, o);
    }
}

// Round 11
// 55.019 us; speedup vs baseline: 2.4908x; 2.4908x over previous
//
#include <hip/hip_runtime.h>
#include <hip/hip_bf16.h>
#include <cstdint>

#define SEQ   2048
#define HD    64
#define NBH   32
#define QBLK  64
#define KVBLK 64
#define NQT   (SEQ / QBLK)  // 32
#define LDK   72            // padded LDS stride (shorts): 144B rows
// scale = 1/sqrt(64) * log2(e)  (softmax in exp2 domain)
#define QSC   0.18033688011112042f
#define THR   11.0f         // defer-max threshold (log2 domain)

typedef __attribute__((ext_vector_type(8))) short short8;
typedef __attribute__((ext_vector_type(4))) float floatx4;

#if __has_builtin(__builtin_amdgcn_exp2f)
#define EXP2(x) __builtin_amdgcn_exp2f(x)
#else
#define EXP2(x) __expf((x) * 0.69314718055994531f)
#endif

static __device__ __forceinline__ short f2bf(float f) {
    union { float f; unsigned u; } x; x.f = f;
    return (short)((x.u + 0x7fffu + ((x.u >> 16) & 1u)) >> 16);  // RNE
}
static __device__ __forceinline__ unsigned pkbf(float a, float b) {
    __hip_bfloat162 h = __float22bfloat162_rn(make_float2(a, b));
    union { __hip_bfloat162 h; unsigned u; } c; c.h = h; return c.u;
}

// ---------------- prep kernels (proven) ----------------

__global__ __launch_bounds__(256)
void conv_k_kernel(const float* __restrict__ K, short* __restrict__ Kb) {
    size_t i = ((size_t)blockIdx.x * 256 + threadIdx.x) * 8;
    float4 a = *(const float4*)(K + i);
    float4 b = *(const float4*)(K + i + 4);
    union { unsigned u[4]; short8 s; } cv;
    cv.u[0] = pkbf(a.x, a.y); cv.u[1] = pkbf(a.z, a.w);
    cv.u[2] = pkbf(b.x, b.y); cv.u[3] = pkbf(b.z, b.w);
    *(short8*)(Kb + i) = cv.s;
}

__global__ __launch_bounds__(256)
void trans_v_kernel(const float* __restrict__ V, short* __restrict__ Vt) {
    __shared__ __align__(16) short Vs[64][72];
    const int tid = threadIdx.x;
    const int bh = blockIdx.x >> 5;
    const int t  = blockIdx.x & 31;
    const float* src = V + ((size_t)bh * SEQ + (size_t)t * 64) * HD;
    #pragma unroll
    for (int i = 0; i < 4; ++i) {
        int idx = i * 256 + tid;
        int r = idx >> 4; int c = (idx & 15) * 4;
        float4 f = *(const float4*)(src + r * HD + c);
        Vs[c + 0][r] = f2bf(f.x); Vs[c + 1][r] = f2bf(f.y);
        Vs[c + 2][r] = f2bf(f.z); Vs[c + 3][r] = f2bf(f.w);
    }
    __syncthreads();
    short* dst = Vt + (size_t)bh * HD * SEQ + t * 64;
    #pragma unroll
    for (int i = 0; i < 2; ++i) {
        int idx = i * 256 + tid;
        int d = idx >> 3; int j = idx & 7;
        short8 v = *(const short8*)&Vs[d][j * 8];
        *(short8*)(dst + (size_t)d * SEQ + j * 8) = v;
    }
}

// ---------------- main attention kernel (v11) ----------------
// = v9 (best: 45.4 us) + (a) speculative exp2 with old max — the fmax tree
// and the two cross-lane shuffles resolve off the critical path; rare
// __any(trig) path recomputes exactly; (b) K/V prefetch issued BEFORE the
// barrier so L2 latency drains during the barrier wait.
// Zero-LDS P via K-row permutation {0,4,32,36}: s_acc[n][r] holds
// S[k = 8*lg + 4*(n&1) + r + 32*(n>>1)][q = l15], so packed P is already the
// PV A-fragment. V staged in LDS [d][kv] (coalesced write, b128 reads).

__global__ __launch_bounds__(256, 4)
void fa_fwd_v11(const float* __restrict__ Q, const short* __restrict__ Kg,
                const short* __restrict__ Vtg, float* __restrict__ O)
{
    const int tid  = threadIdx.x;
    const int lane = tid & 63;
    const int wv   = tid >> 6;
    const int l15  = lane & 15;
    const int lg   = lane >> 4;
    const int lg4  = lg * 4;
    const int dofs = lg * 8;

    const int bh = blockIdx.x & (NBH - 1);
    const int qi = (NQT - 1) - (blockIdx.x >> 5);   // heavy tiles first
    const int qbase = qi * QBLK;

    const float* Qp = Q   + (size_t)bh * SEQ * HD;
    const short* Kp = Kg  + (size_t)bh * SEQ * HD;
    const short* Vp = Vtg + (size_t)bh * HD * SEQ;
    float*       Op = O   + (size_t)bh * SEQ * HD;

    __shared__ __align__(16) short K_lds[2][KVBLK][LDK];
    __shared__ __align__(16) short Vt_lds[2][HD][LDK];

    const int r0 = tid >> 3,         j0 = tid & 7;
    const int r1 = (tid + 256) >> 3, j1 = tid & 7;
    const int kg0 = r0 * HD + j0 * 8, kg1 = r1 * HD + j1 * 8;
    const int vg0 = r0 * SEQ + j0 * 8, vg1 = r1 * SEQ + j1 * 8;

    // permuted K-row base: call n reads row rowb + {0,4,32,36}[n]
    const int rowb = ((l15 & ~3) << 1) + (l15 & 3);   // 8*(l15>>2) + (l15&3)
    const int kb   = 8 * lg;                           // lane's k base

    // ---- Q fragments (B-operand), scale folded ----
    short8 qf0, qf1;
    {
        const float* src = Qp + (size_t)(qbase + wv * 16 + l15) * HD + dofs;
        union { unsigned u[4]; short8 s; } cv;
        float4 f0 = *(const float4*)(src);
        float4 f1 = *(const float4*)(src + 4);
        cv.u[0] = pkbf(f0.x * QSC, f0.y * QSC); cv.u[1] = pkbf(f0.z * QSC, f0.w * QSC);
        cv.u[2] = pkbf(f1.x * QSC, f1.y * QSC); cv.u[3] = pkbf(f1.z * QSC, f1.w * QSC);
        qf0 = cv.s;
        f0 = *(const float4*)(src + 32);
        f1 = *(const float4*)(src + 36);
        cv.u[0] = pkbf(f0.x * QSC, f0.y * QSC); cv.u[1] = pkbf(f0.z * QSC, f0.w * QSC);
        cv.u[2] = pkbf(f1.x * QSC, f1.y * QSC); cv.u[3] = pkbf(f1.z * QSC, f1.w * QSC);
        qf1 = cv.s;
    }

    // ---- prologue: prefetch tile 0 into registers ----
    short8 krA = *(const short8*)(Kp + kg0);
    short8 krB = *(const short8*)(Kp + kg1);
    short8 vrA = *(const short8*)(Vp + vg0);
    short8 vrB = *(const short8*)(Vp + vg1);

    floatx4 o_acc[4];
    #pragma unroll
    for (int dt = 0; dt < 4; ++dt)
        #pragma unroll
        for (int e = 0; e < 4; ++e) o_acc[dt][e] = 0.0f;
    float m_s = -1e30f, l_s = 0.0f;

    for (int t = 0; t <= qi; ++t) {
        const int buf = t & 1;
        // ---- publish tile t (regs -> LDS) ----
        *(short8*)&K_lds[buf][r0][j0 * 8]  = krA;
        *(short8*)&K_lds[buf][r1][j1 * 8]  = krB;
        *(short8*)&Vt_lds[buf][r0][j0 * 8] = vrA;
        *(short8*)&Vt_lds[buf][r1][j1 * 8] = vrB;

        // ---- issue tile t+1 loads BEFORE the barrier (latency drains in it) ----
        if (t < qi) {
            const short* ks = Kp + (size_t)(t + 1) * KVBLK * HD;
            const short* vs = Vp + (t + 1) * KVBLK;
            krA = *(const short8*)(ks + kg0);
            krB = *(const short8*)(ks + kg1);
            vrA = *(const short8*)(vs + vg0);
            vrB = *(const short8*)(vs + vg1);
        }
        __syncthreads();   // tile t visible; prior buf's readers done

        // ---- S^T = K (Q*scale)^T with permuted rows ----
        const int roff[4] = {0, 4, 32, 36};
        floatx4 s_acc[4];
        __builtin_amdgcn_s_setprio(1);
        #pragma unroll
        for (int n = 0; n < 4; ++n) {
            const short* krow = &K_lds[buf][rowb + roff[n]][0];
            const short8 k0 = *(const short8*)(krow + dofs);
            const short8 k1 = *(const short8*)(krow + dofs + 32);
            floatx4 acc = {0.0f, 0.0f, 0.0f, 0.0f};
            acc = __builtin_amdgcn_mfma_f32_16x16x32_bf16(k0, qf0, acc, 0, 0, 0);
            acc = __builtin_amdgcn_mfma_f32_16x16x32_bf16(k1, qf1, acc, 0, 0, 0);
            s_acc[n] = acc;
        }
        __builtin_amdgcn_s_setprio(0);

        // ---- causal mask (diagonal tile only): k_local > q_local ----
        if (t == qi) {
            const int qlocal = wv * 16 + l15;
            #pragma unroll
            for (int n = 0; n < 4; ++n)
                #pragma unroll
                for (int r = 0; r < 4; ++r)
                    if (kb + roff[n] + r > qlocal) s_acc[n][r] = -1e30f;
        }

        // ---- SPECULATIVE P = exp2(S - m_old); max tree+shfls off-path ----
        float p00 = EXP2(s_acc[0][0] - m_s), p01 = EXP2(s_acc[0][1] - m_s);
        float p02 = EXP2(s_acc[0][2] - m_s), p03 = EXP2(s_acc[0][3] - m_s);
        float p10 = EXP2(s_acc[1][0] - m_s), p11 = EXP2(s_acc[1][1] - m_s);
        float p12 = EXP2(s_acc[1][2] - m_s), p13 = EXP2(s_acc[1][3] - m_s);
        float p20 = EXP2(s_acc[2][0] - m_s), p21 = EXP2(s_acc[2][1] - m_s);
        float p22 = EXP2(s_acc[2][2] - m_s), p23 = EXP2(s_acc[2][3] - m_s);
        float p30 = EXP2(s_acc[3][0] - m_s), p31 = EXP2(s_acc[3][1] - m_s);
        float p32 = EXP2(s_acc[3][2] - m_s), p33 = EXP2(s_acc[3][3] - m_s);
        float lsum = ((p00 + p01) + (p02 + p03)) + ((p10 + p11) + (p12 + p13))
                   + ((p20 + p21) + (p22 + p23)) + ((p30 + p31) + (p32 + p33));

        float t0 = fmaxf(fmaxf(s_acc[0][0], s_acc[0][1]), fmaxf(s_acc[0][2], s_acc[0][3]));
        float t1 = fmaxf(fmaxf(s_acc[1][0], s_acc[1][1]), fmaxf(s_acc[1][2], s_acc[1][3]));
        float t2 = fmaxf(fmaxf(s_acc[2][0], s_acc[2][1]), fmaxf(s_acc[2][2], s_acc[2][3]));
        float t3 = fmaxf(fmaxf(s_acc[3][0], s_acc[3][1]), fmaxf(s_acc[3][2], s_acc[3][3]));
        float rmax = fmaxf(fmaxf(t0, t1), fmaxf(t2, t3));
        rmax = fmaxf(rmax, __shfl_xor(rmax, 16));
        rmax = fmaxf(rmax, __shfl_xor(rmax, 32));

        const bool trig = rmax > m_s + THR;
        if (__any(trig)) {                       // rare after the first tile
            float alpha = 1.0f;
            if (trig) {
                alpha = EXP2(m_s - rmax);        // 0 on the first tile
                m_s = rmax;
                p00 = EXP2(s_acc[0][0] - m_s); p01 = EXP2(s_acc[0][1] - m_s);
                p02 = EXP2(s_acc[0][2] - m_s); p03 = EXP2(s_acc[0][3] - m_s);
                p10 = EXP2(s_acc[1][0] - m_s); p11 = EXP2(s_acc[1][1] - m_s);
                p12 = EXP2(s_acc[1][2] - m_s); p13 = EXP2(s_acc[1][3] - m_s);
                p20 = EXP2(s_acc[2][0] - m_s); p21 = EXP2(s_acc[2][1] - m_s);
                p22 = EXP2(s_acc[2][2] - m_s); p23 = EXP2(s_acc[2][3] - m_s);
                p30 = EXP2(s_acc[3][0] - m_s); p31 = EXP2(s_acc[3][1] - m_s);
                p32 = EXP2(s_acc[3][2] - m_s); p33 = EXP2(s_acc[3][3] - m_s);
                lsum = ((p00 + p01) + (p02 + p03)) + ((p10 + p11) + (p12 + p13))
                     + ((p20 + p21) + (p22 + p23)) + ((p30 + p31) + (p32 + p33));
            }
            l_s = l_s * alpha + lsum;
            float a0 = __shfl(alpha, lg4 + 0);
            float a1 = __shfl(alpha, lg4 + 1);
            float a2 = __shfl(alpha, lg4 + 2);
            float a3 = __shfl(alpha, lg4 + 3);
            #pragma unroll
            for (int dt = 0; dt < 4; ++dt) {
                o_acc[dt][0] *= a0; o_acc[dt][1] *= a1;
                o_acc[dt][2] *= a2; o_acc[dt][3] *= a3;
            }
        } else {
            l_s += lsum;
        }

        // ---- pack P into PV A-fragments (in-register, zero LDS) ----
        short8 p0, p1;
        {
            union { unsigned u[4]; short8 s; } c0, c1;
            c0.u[0] = pkbf(p00, p01); c0.u[1] = pkbf(p02, p03);
            c0.u[2] = pkbf(p10, p11); c0.u[3] = pkbf(p12, p13);
            c1.u[0] = pkbf(p20, p21); c1.u[1] = pkbf(p22, p23);
            c1.u[2] = pkbf(p30, p31); c1.u[3] = pkbf(p32, p33);
            p0 = c0.s; p1 = c1.s;
        }

        // ---- O += P V ----
        __builtin_amdgcn_s_setprio(1);
        #pragma unroll
        for (int dt = 0; dt < 4; ++dt) {
            const short8 v0 = *(const short8*)&Vt_lds[buf][dt * 16 + l15][dofs];
            const short8 v1 = *(const short8*)&Vt_lds[buf][dt * 16 + l15][dofs + 32];
            o_acc[dt] = __builtin_amdgcn_mfma_f32_16x16x32_bf16(p0, v0, o_acc[dt], 0, 0, 0);
            o_acc[dt] = __builtin_amdgcn_mfma_f32_16x16x32_bf16(p1, v1, o_acc[dt], 0, 0, 0);
        }
        __builtin_amdgcn_s_setprio(0);
    }

    // ---- finalize ----
    l_s += __shfl_xor(l_s, 16);
    l_s += __shfl_xor(l_s, 32);
    const float linv = 1.0f / l_s;
    #pragma unroll
    for (int e = 0; e < 4; ++e) {
        const float li = __shfl(linv, lg4 + e);
        const int row = qbase + wv * 16 + lg4 + e;
        #pragma unroll
        for (int dt = 0; dt < 4; ++dt)
            Op[(size_t)row * HD + dt * 16 + l15] = o_acc[dt][e] * li;
    }
}

// ---------------- fallback (round-1 kernel, proven) if ws too small ----------------

__global__ __launch_bounds__(256, 2)
void fa_fwd_v1(const float* __restrict__ Q, const float* __restrict__ K,
               const float* __restrict__ V, float* __restrict__ O)
{
    const int tid  = threadIdx.x;
    const int lane = tid & 63;
    const int wv   = tid >> 6;
    const int l15  = lane & 15;
    const int lg   = lane >> 4;
    const int dofs = lg * 8;
    const int bh = blockIdx.x & (NBH - 1);
    const int qi = 31 - (blockIdx.x >> 5);
    const size_t base = (size_t)bh * SEQ * HD;
    const float* Qp = Q + base; const float* Kp = K + base;
    const float* Vp = V + base; float* Op = O + base;
    const int qbase = qi * 64;
    __shared__ __align__(16) short K_lds[64][72];
    __shared__ __align__(16) short Vt_lds[HD][72];
    __shared__ __align__(16) short P_lds[4][16][72];
    short8 qfrag[2];
    {
        const float* src = Qp + (size_t)(qbase + wv * 16 + l15) * HD + dofs;
        #pragma unroll
        for (int c = 0; c < 2; ++c) {
            float4 f0 = *(const float4*)(src + 32 * c);
            float4 f1 = *(const float4*)(src + 32 * c + 4);
            short8 tt;
            tt[0] = f2bf(f0.x * 0.125f); tt[1] = f2bf(f0.y * 0.125f);
            tt[2] = f2bf(f0.z * 0.125f); tt[3] = f2bf(f0.w * 0.125f);
            tt[4] = f2bf(f1.x * 0.125f); tt[5] = f2bf(f1.y * 0.125f);
            tt[6] = f2bf(f1.z * 0.125f); tt[7] = f2bf(f1.w * 0.125f);
            qfrag[c] = tt;
        }
    }
    floatx4 o_acc[4];
    #pragma unroll
    for (int dt = 0; dt < 4; ++dt)
        #pragma unroll
        for (int e = 0; e < 4; ++e) o_acc[dt][e] = 0.0f;
    float m_r[4], l_r[4];
    #pragma unroll
    for (int r = 0; r < 4; ++r) { m_r[r] = -1e30f; l_r[r] = 0.0f; }
    for (int t = 0; t <= qi; ++t) {
        __syncthreads();
        {
            const float4* ks = (const float4*)(Kp + (size_t)t * 64 * HD);
            const float4* vs = (const float4*)(Vp + (size_t)t * 64 * HD);
            #pragma unroll
            for (int j = 0; j < 4; ++j) {
                int idx = j * 256 + tid;
                int row = idx >> 4;
                int col = (idx & 15) << 2;
                float4 kf = ks[idx];
                K_lds[row][col + 0] = f2bf(kf.x); K_lds[row][col + 1] = f2bf(kf.y);
                K_lds[row][col + 2] = f2bf(kf.z); K_lds[row][col + 3] = f2bf(kf.w);
                float4 vf = vs[idx];
                Vt_lds[col + 0][row] = f2bf(vf.x); Vt_lds[col + 1][row] = f2bf(vf.y);
                Vt_lds[col + 2][row] = f2bf(vf.z); Vt_lds[col + 3][row] = f2bf(vf.w);
            }
        }
        __syncthreads();
        floatx4 s_acc[4];
        #pragma unroll
        for (int n = 0; n < 4; ++n) {
            const short8 k0 = *(const short8*)&K_lds[n * 16 + l15][dofs];
            const short8 k1 = *(const short8*)&K_lds[n * 16 + l15][dofs + 32];
            floatx4 acc = {0.0f, 0.0f, 0.0f, 0.0f};
            acc = __builtin_amdgcn_mfma_f32_16x16x32_bf16(qfrag[0], k0, acc, 0, 0, 0);
            acc = __builtin_amdgcn_mfma_f32_16x16x32_bf16(qfrag[1], k1, acc, 0, 0, 0);
            s_acc[n] = acc;
        }
        if (t == qi) {
            #pragma unroll
            for (int n = 0; n < 4; ++n)
                #pragma unroll
                for (int r = 0; r < 4; ++r) {
                    int qr = wv * 16 + lg * 4 + r;
                    int kc = n * 16 + l15;
                    if (kc > qr) s_acc[n][r] = -1e30f;
                }
        }
        #pragma unroll
        for (int r = 0; r < 4; ++r) {
            float rmax = fmaxf(fmaxf(s_acc[0][r], s_acc[1][r]),
                               fmaxf(s_acc[2][r], s_acc[3][r]));
            rmax = fmaxf(rmax, __shfl_xor(rmax, 1));
            rmax = fmaxf(rmax, __shfl_xor(rmax, 2));
            rmax = fmaxf(rmax, __shfl_xor(rmax, 4));
            rmax = fmaxf(rmax, __shfl_xor(rmax, 8));
            float mnew  = fmaxf(m_r[r], rmax);
            float alpha = __expf(m_r[r] - mnew);
            m_r[r] = mnew;
            l_r[r] *= alpha;
            #pragma unroll
            for (int dt = 0; dt < 4; ++dt) o_acc[dt][r] *= alpha;
            #pragma unroll
            for (int n = 0; n < 4; ++n) {
                float p = __expf(s_acc[n][r] - mnew);
                l_r[r] += p;
                P_lds[wv][lg * 4 + r][n * 16 + l15] = f2bf(p);
            }
        }
        asm volatile("s_waitcnt lgkmcnt(0)" ::: "memory");
        const short8 p0 = *(const short8*)&P_lds[wv][l15][dofs];
        const short8 p1 = *(const short8*)&P_lds[wv][l15][dofs + 32];
        #pragma unroll
        for (int dt = 0; dt < 4; ++dt) {
            const short8 v0 = *(const short8*)&Vt_lds[dt * 16 + l15][dofs];
            const short8 v1 = *(const short8*)&Vt_lds[dt * 16 + l15][dofs + 32];
            o_acc[dt] = __builtin_amdgcn_mfma_f32_16x16x32_bf16(p0, v0, o_acc[dt], 0, 0, 0);
            o_acc[dt] = __builtin_amdgcn_mfma_f32_16x16x32_bf16(p1, v1, o_acc[dt], 0, 0, 0);
        }
    }
    #pragma unroll
    for (int r = 0; r < 4; ++r) {
        float l = l_r[r];
        l += __shfl_xor(l, 1);
        l += __shfl_xor(l, 2);
        l += __shfl_xor(l, 4);
        l += __shfl_xor(l, 8);
        l_r[r] = 1.0f / l;
    }
    #pragma unroll
    for (int dt = 0; dt < 4; ++dt)
        #pragma unroll
        for (int r = 0; r < 4; ++r) {
            int row = qbase + wv * 16 + lg * 4 + r;
            Op[(size_t)row * HD + dt * 16 + l15] = o_acc[dt][r] * l_r[r];
        }
}

extern "C" void kernel_launch(void* const* d_in, const int* in_sizes, int n_in,
                              void* d_out, int out_size, void* d_ws, size_t ws_size,
                              hipStream_t stream) {
    const float* q = (const float*)d_in[0];
    const float* k = (const float*)d_in[1];
    const float* v = (const float*)d_in[2];
    float* o = (float*)d_out;
    (void)in_sizes; (void)n_in; (void)out_size;

    const size_t elems = (size_t)NBH * SEQ * HD;
    const size_t need  = 2 * elems * sizeof(short);
    if (ws_size >= need) {
        short* kb = (short*)d_ws;
        short* vt = kb + elems;
        conv_k_kernel<<<dim3(elems / (256 * 8)), dim3(256), 0, stream>>>(k, kb);
        trans_v_kernel<<<dim3(NBH * 32), dim3(256), 0, stream>>>(v, vt);
        fa_fwd_v11<<<dim3(NBH * NQT), dim3(256), 0, stream>>>(q, kb, vt, o);
    } else {
        fa_fwd_v1<<<dim3(NBH * 32), dim3(256), 0, stream>>>(q, k, v, o);
    }
}